// Round 2
// baseline (234.505 us; speedup 1.0000x reference)
//
#include <hip/hip_runtime.h>
#include <hip/hip_fp16.h>

#define N_NODES 65536
#define N_EDGES 1048576
#define NBUCK 256                 // coarse buckets (dst>>8), 256 nodes each
#define PBLOCKS 1024              // partition blocks (4 blocks/CU)
#define EPB (N_EDGES / PBLOCKS)   // 1024 edges per partition block
#define K4CAP 6144                // finalize LDS staging capacity (mean 4096, sigma 64)
#define GB1 (N_NODES / 64)        // gemm1 blocks (1024); hist blocks appended after
constexpr float NEG = 0.2f;
constexpr float EPS_ = 1e-16f;
constexpr float WSHIFT = 2.7725887f;   // ln(16): softmax-invariant shift, fp16 overflow guard

typedef __attribute__((ext_vector_type(8))) short bf16x8;
typedef __attribute__((ext_vector_type(4))) float f32x4;

__device__ __forceinline__ unsigned short f2bf(float f) {
    unsigned int u = __float_as_uint(f);
    return (unsigned short)((u + 0x7fffu + ((u >> 16) & 1u)) >> 16);
}
__device__ __forceinline__ unsigned short f2h(float f) {
    __half_raw r = __half_raw(__float2half(f));
    return r.x;
}
__device__ __forceinline__ __half2 u2h2(unsigned int u) {
    union { unsigned int u; __half2 h; } c; c.u = u; return c.h;
}
__device__ __forceinline__ unsigned int h22u(__half2 h) {
    union { unsigned int u; __half2 h; } c; c.h = h; return c.u;
}
__device__ __forceinline__ float lrelu_exp_s(float l) {
    return __expf(fmaxf(l, NEG * l) - WSHIFT);
}

// ---------------- CSR build: radix partition by dst>>8, no global atomics ----------------
// hist_mat/cursor_mat: [bucket][pblock] (bucket-major), NBUCK x PBLOCKS
// (coarse_hist is fused into gemm1_hist below)

// scan_a: block-local exclusive scan of the 256K-entry matrix (1024/block)
__global__ __launch_bounds__(1024) void scan_a(const int* __restrict__ in,
                                               int* __restrict__ out,
                                               int* __restrict__ bsum) {
    __shared__ int sm[1024];
    int t = threadIdx.x, i = blockIdx.x * 1024 + t;
    int v = in[i];
    sm[t] = v;
    __syncthreads();
    for (int off = 1; off < 1024; off <<= 1) {
        int u = (t >= off) ? sm[t - off] : 0;
        __syncthreads();
        sm[t] += u;
        __syncthreads();
    }
    out[i] = sm[t] - v;
    if (t == 1023) bsum[blockIdx.x] = sm[t];
}

// scan_c: adds exclusive prefix of raw block sums (scan_b folded in: each block
// reduces bsum[0..blockIdx) itself — 256 values, one wave-reduce)
__global__ __launch_bounds__(1024) void scan_c(int* __restrict__ arr,
                                               const int* __restrict__ bsum) {
    __shared__ int partial[4];
    int t = threadIdx.x;
    if (t < 256) {
        int v = (t < (int)blockIdx.x) ? bsum[t] : 0;
        #pragma unroll
        for (int msk = 1; msk < 64; msk <<= 1) v += __shfl_xor(v, msk);
        if ((t & 63) == 0) partial[t >> 6] = v;
    }
    __syncthreads();
    int pref = partial[0] + partial[1] + partial[2] + partial[3];
    arr[blockIdx.x * 1024 + t] += pref;
}

__global__ __launch_bounds__(256) void partition_kernel(const int* __restrict__ ei,
                                                        const int* __restrict__ cursor_mat,
                                                        unsigned int* __restrict__ edge_part) {
    __shared__ int h[NBUCK];
    __shared__ int start[NBUCK];
    __shared__ int cur[NBUCK];
    __shared__ int gcur[NBUCK];
    __shared__ unsigned int stage[EPB];
    int t = threadIdx.x;
    h[t] = 0;
    gcur[t] = cursor_mat[t * PBLOCKS + blockIdx.x];
    __syncthreads();
    unsigned int ent[EPB / 256];
    int base = blockIdx.x * EPB;
    #pragma unroll
    for (int i = 0; i < EPB / 256; ++i) {
        int e = base + i * 256 + t;
        int s = ei[e], d = ei[N_EDGES + e];
        ent[i] = ((unsigned int)s << 16) | (unsigned int)d;   // src,dst both < 2^16
        atomicAdd(&h[d >> 8], 1);
    }
    __syncthreads();
    int v = h[t];
    start[t] = v;
    __syncthreads();
    for (int off = 1; off < 256; off <<= 1) {
        int u = (t >= off) ? start[t - off] : 0;
        __syncthreads();
        start[t] += u;
        __syncthreads();
    }
    int excl = start[t] - v;
    start[t] = excl;
    cur[t] = excl;
    __syncthreads();
    #pragma unroll
    for (int i = 0; i < EPB / 256; ++i) {
        int b = (int)((ent[i] & 0xffffu) >> 8);
        int slot = atomicAdd(&cur[b], 1);
        stage[slot] = ent[i];
    }
    __syncthreads();
    int s0 = t * (EPB / 256);
    #pragma unroll
    for (int i = 0; i < EPB / 256; ++i) {
        unsigned int p = stage[s0 + i];
        int b = (int)((p & 0xffffu) >> 8);
        edge_part[gcur[b] + (s0 + i - start[b])] = p;
    }
}

// finalize: 1024 threads/block (16 waves/CU), csr_src as ushort
__global__ __launch_bounds__(1024) void finalize_kernel(const unsigned int* __restrict__ edge_part,
                                                        const int* __restrict__ cursor_mat,
                                                        int* __restrict__ row_ptr,
                                                        unsigned short* __restrict__ csr16) {
    __shared__ int h[256];
    __shared__ int sc[256];
    __shared__ int cur[256];
    __shared__ unsigned short stage[K4CAP];
    int t = threadIdx.x;
    int b = blockIdx.x;
    if (b == NBUCK - 1 && t == 0) row_ptr[N_NODES] = N_EDGES;
    int cs = cursor_mat[b * PBLOCKS];
    int ce = (b == NBUCK - 1) ? N_EDGES : cursor_mat[(b + 1) * PBLOCKS];
    int cnt = ce - cs;
    if (t < 256) h[t] = 0;
    __syncthreads();
    for (int i = t; i < cnt; i += 1024)
        atomicAdd(&h[edge_part[cs + i] & 0xffu], 1);
    __syncthreads();
    int v = 0;
    if (t < 256) { v = h[t]; sc[t] = v; }
    __syncthreads();
    for (int off = 1; off < 256; off <<= 1) {
        int u = (t < 256 && t >= off) ? sc[t - off] : 0;
        __syncthreads();
        if (t < 256) sc[t] += u;
        __syncthreads();
    }
    if (t < 256) {
        int excl = sc[t] - v;
        row_ptr[b * 256 + t] = cs + excl;
        cur[t] = excl;
    }
    __syncthreads();
    if (cnt <= K4CAP) {
        for (int i = t; i < cnt; i += 1024) {
            unsigned int p = edge_part[cs + i];
            int slot = atomicAdd(&cur[p & 0xffu], 1);
            stage[slot] = (unsigned short)(p >> 16);
        }
        __syncthreads();
        for (int i = t; i < cnt; i += 1024)
            csr16[cs + i] = stage[i];
    } else {
        for (int i = t; i < cnt; i += 1024) {
            unsigned int p = edge_part[cs + i];
            int slot = atomicAdd(&cur[p & 0xffu], 1);
            csr16[cs + slot] = (unsigned short)(p >> 16);
        }
    }
}

// ---------------- GEMM via MFMA 16x16x32 bf16 (fp32 accum, fp16 out) ----------------
// layer 1: fp32 X input; att1 fused into epilogue (a_src/a_dst from fp32 accumulators);
// coarse_hist fused as trailing block range (BW-light, hides under MFMA blocks).

__global__ __launch_bounds__(256) void gemm1_hist(const float* __restrict__ X,
                                                  const float* __restrict__ W,
                                                  const float* __restrict__ as_w,
                                                  const float* __restrict__ ad_w,
                                                  const int* __restrict__ ei,
                                                  unsigned short* __restrict__ H,
                                                  float* __restrict__ a_src,
                                                  float* __restrict__ a_dst,
                                                  int* __restrict__ hist_mat) {
    extern __shared__ unsigned short Wl[];
    int t = threadIdx.x;
    if (blockIdx.x >= GB1) {
        // ---- coarse histogram path (block-uniform branch) ----
        int* hs = (int*)Wl;
        int pb = blockIdx.x - GB1;
        hs[t] = 0;
        __syncthreads();
        int base = pb * EPB;
        #pragma unroll
        for (int i = 0; i < EPB / 256; ++i) {
            int d = ei[N_EDGES + base + i * 256 + t];
            atomicAdd(&hs[d >> 8], 1);
        }
        __syncthreads();
        hist_mat[t * PBLOCKS + pb] = hs[t];
        return;
    }
    constexpr int OUTC = 128;
    constexpr int NT = OUTC / 16;
    for (int idx = t; idx < OUTC * 128; idx += 256) {
        int j = idx & 7;
        int ln = (idx >> 3) & 63;
        int fc = idx >> 9;
        int kc = fc & 3, ct = fc >> 2;
        int k = kc * 32 + (ln >> 4) * 8 + j;
        int nn = ct * 16 + (ln & 15);
        Wl[idx] = (unsigned short)f2bf(W[k * OUTC + nn]);
    }
    __syncthreads();
    int wave = t >> 6, lane = t & 63;
    int m = lane & 15, quad = lane >> 4;
    int node_base = blockIdx.x * 64 + wave * 16;
    const float* xrow = X + (size_t)(node_base + m) * 128 + quad * 8;
    bf16x8 a[4];
    #pragma unroll
    for (int kc = 0; kc < 4; ++kc) {
        float4 u = *(const float4*)(xrow + kc * 32);
        float4 v = *(const float4*)(xrow + kc * 32 + 4);
        bf16x8 af;
        af[0] = (short)f2bf(u.x); af[1] = (short)f2bf(u.y);
        af[2] = (short)f2bf(u.z); af[3] = (short)f2bf(u.w);
        af[4] = (short)f2bf(v.x); af[5] = (short)f2bf(v.y);
        af[6] = (short)f2bf(v.z); af[7] = (short)f2bf(v.w);
        a[kc] = af;
    }
    float asv[NT], adv[NT];
    #pragma unroll
    for (int ct = 0; ct < NT; ++ct) {
        asv[ct] = as_w[ct * 16 + m];
        adv[ct] = ad_w[ct * 16 + m];
    }
    float ps[4][4] = {};
    float pd[4][4] = {};
    #pragma unroll
    for (int ct = 0; ct < NT; ++ct) {
        f32x4 acc = {0.f, 0.f, 0.f, 0.f};
        #pragma unroll
        for (int kc = 0; kc < 4; ++kc) {
            bf16x8 bfr = *(const bf16x8*)(Wl + ((ct * 4 + kc) * 64 + lane) * 8);
            acc = __builtin_amdgcn_mfma_f32_16x16x32_bf16(a[kc], bfr, acc, 0, 0, 0);
        }
        int hh = ct >> 1;   // head = channel>>5 = ct>>1 (m<16)
        #pragma unroll
        for (int r = 0; r < 4; ++r) {
            H[(size_t)(node_base + quad * 4 + r) * OUTC + ct * 16 + m] = f2h(acc[r]);
            ps[r][hh] += acc[r] * asv[ct];
            pd[r][hh] += acc[r] * adv[ct];
        }
    }
    // reduce partial dots across the 16 m-lanes (quad-preserving masks)
    #pragma unroll
    for (int r = 0; r < 4; ++r) {
        #pragma unroll
        for (int hh = 0; hh < 4; ++hh) {
            float s = ps[r][hh], d = pd[r][hh];
            #pragma unroll
            for (int msk = 1; msk < 16; msk <<= 1) {
                s += __shfl_xor(s, msk);
                d += __shfl_xor(d, msk);
            }
            if (m == 0) {
                int node = node_base + quad * 4 + r;
                a_src[node * 4 + hh] = s;
                a_dst[node * 4 + hh] = d;
            }
        }
    }
}

// layer 2: bf16 X input; att2 fused into epilogue

__global__ __launch_bounds__(256) void gemm2_mfma(const unsigned short* __restrict__ X,
                                                  const float* __restrict__ W,
                                                  const float* __restrict__ as_w,
                                                  const float* __restrict__ ad_w,
                                                  unsigned short* __restrict__ H,
                                                  float* __restrict__ a_src,
                                                  float* __restrict__ a_dst) {
    constexpr int OUTC = 64;
    constexpr int NT = OUTC / 16;
    extern __shared__ unsigned short Wl[];
    int t = threadIdx.x;
    for (int idx = t; idx < OUTC * 128; idx += 256) {
        int j = idx & 7;
        int ln = (idx >> 3) & 63;
        int fc = idx >> 9;
        int kc = fc & 3, ct = fc >> 2;
        int k = kc * 32 + (ln >> 4) * 8 + j;
        int nn = ct * 16 + (ln & 15);
        Wl[idx] = (unsigned short)f2bf(W[k * OUTC + nn]);
    }
    __syncthreads();
    int wave = t >> 6, lane = t & 63;
    int m = lane & 15, quad = lane >> 4;
    int node_base = blockIdx.x * 64 + wave * 16;
    const unsigned short* xrow = X + (size_t)(node_base + m) * 128 + quad * 8;
    bf16x8 a[4];
    #pragma unroll
    for (int kc = 0; kc < 4; ++kc) a[kc] = *(const bf16x8*)(xrow + kc * 32);
    float asv[NT], adv[NT];
    #pragma unroll
    for (int ct = 0; ct < NT; ++ct) {
        asv[ct] = as_w[ct * 16 + m];
        adv[ct] = ad_w[ct * 16 + m];
    }
    float ps[4] = {};
    float pd[4] = {};
    #pragma unroll
    for (int ct = 0; ct < NT; ++ct) {
        f32x4 acc = {0.f, 0.f, 0.f, 0.f};
        #pragma unroll
        for (int kc = 0; kc < 4; ++kc) {
            bf16x8 bfr = *(const bf16x8*)(Wl + ((ct * 4 + kc) * 64 + lane) * 8);
            acc = __builtin_amdgcn_mfma_f32_16x16x32_bf16(a[kc], bfr, acc, 0, 0, 0);
        }
        #pragma unroll
        for (int r = 0; r < 4; ++r) {
            H[(size_t)(node_base + quad * 4 + r) * OUTC + ct * 16 + m] = f2h(acc[r]);
            ps[r] += acc[r] * asv[ct];
            pd[r] += acc[r] * adv[ct];
        }
    }
    #pragma unroll
    for (int r = 0; r < 4; ++r) {
        float s = ps[r], d = pd[r];
        #pragma unroll
        for (int msk = 1; msk < 16; msk <<= 1) {
            s += __shfl_xor(s, msk);
            d += __shfl_xor(d, msk);
        }
        if (m == 0) {
            int node = node_base + quad * 4 + r;
            a_src[node] = s;
            a_dst[node] = d;
        }
    }
}

// ---------------- edge aggregation: TWO nodes per wave, 16 edges/node/iter ----------
// Two 8-edge sub-batches per iteration; all 8 (agg1) / 4 (agg2) row-gathers are
// issued before any hfma consumes them — doubles outstanding loads per SIMD.

__global__ __launch_bounds__(256, 8) void agg1_kernel(const int* __restrict__ row_ptr,
                                                      const unsigned short* __restrict__ csr16,
                                                      const unsigned int* __restrict__ h1u,
                                                      const float* __restrict__ a_src,
                                                      const float* __restrict__ a_dst,
                                                      const float* __restrict__ b1,
                                                      unsigned short* __restrict__ x2) {
    int wave = (blockIdx.x * 256 + threadIdx.x) >> 6;
    int lane = threadIdx.x & 63;
    int half = lane >> 5;
    int ln = lane & 31;
    int n = wave * 2 + half;
    int j8 = ln & 7;               // batch edge slot
    int whead = ln >> 3;           // head for w-compute
    int sub = ln >> 4;             // row-slot within half (0/1)
    int col = ln & 15;             // channel group: ch col*8..+7
    int hd_c = col >> 2;           // head of this lane's channels
    int rbase = half * 32 + hd_c * 8 + sub;   // pack-lane base (+ g*2)
    float adw = a_dst[n * 4 + whead];
    const unsigned int* h1c = h1u + col * 4;
    const float* asw = a_src + whead;
    int e = row_ptr[n], end = row_ptr[n + 1];
    __half2 acc0 = u2h2(0u), acc1 = u2h2(0u), acc2 = u2h2(0u), acc3 = u2h2(0u);
    float denom = 0.f;
    while (e < end) {
        int rem = end - e;
        int mbA = rem > 8 ? 8 : rem;
        int remB = rem - 8;
        int mbB = remB > 8 ? 8 : (remB > 0 ? remB : 0);
        int idxA = e + (j8 < mbA ? j8 : 0);
        int idxB = (remB > 0) ? (e + 8 + (j8 < mbB ? j8 : 0)) : idxA;
        int sA = (int)csr16[idxA];
        int sB = (int)csr16[idxB];
        float lA = asw[sA * 4] + adw;
        float lB = asw[sB * 4] + adw;
        float wA = (j8 < mbA) ? lrelu_exp_s(lA) : 0.f;
        float wB = (j8 < mbB) ? lrelu_exp_s(lB) : 0.f;
        denom += wA + wB;
        unsigned int curA = ((unsigned int)f2h(wA) << 16) | (unsigned int)sA;
        unsigned int curB = ((unsigned int)f2h(wB) << 16) | (unsigned int)sB;
        unsigned int pkA0 = __shfl(curA, rbase);
        unsigned int pkA1 = __shfl(curA, rbase + 2);
        unsigned int pkA2 = __shfl(curA, rbase + 4);
        unsigned int pkA3 = __shfl(curA, rbase + 6);
        unsigned int pkB0 = __shfl(curB, rbase);
        unsigned int pkB1 = __shfl(curB, rbase + 2);
        unsigned int pkB2 = __shfl(curB, rbase + 4);
        unsigned int pkB3 = __shfl(curB, rbase + 6);
        uint4 hvA0 = *(const uint4*)(h1c + (size_t)(pkA0 & 0xffffu) * 64);
        uint4 hvA1 = *(const uint4*)(h1c + (size_t)(pkA1 & 0xffffu) * 64);
        uint4 hvA2 = *(const uint4*)(h1c + (size_t)(pkA2 & 0xffffu) * 64);
        uint4 hvA3 = *(const uint4*)(h1c + (size_t)(pkA3 & 0xffffu) * 64);
        uint4 hvB0 = *(const uint4*)(h1c + (size_t)(pkB0 & 0xffffu) * 64);
        uint4 hvB1 = *(const uint4*)(h1c + (size_t)(pkB1 & 0xffffu) * 64);
        uint4 hvB2 = *(const uint4*)(h1c + (size_t)(pkB2 & 0xffffu) * 64);
        uint4 hvB3 = *(const uint4*)(h1c + (size_t)(pkB3 & 0xffffu) * 64);
        unsigned int wu; __half2 w2;
        wu = pkA0 >> 16; w2 = u2h2(wu | (wu << 16));
        acc0 = __hfma2(w2, u2h2(hvA0.x), acc0);
        acc1 = __hfma2(w2, u2h2(hvA0.y), acc1);
        acc2 = __hfma2(w2, u2h2(hvA0.z), acc2);
        acc3 = __hfma2(w2, u2h2(hvA0.w), acc3);
        wu = pkA1 >> 16; w2 = u2h2(wu | (wu << 16));
        acc0 = __hfma2(w2, u2h2(hvA1.x), acc0);
        acc1 = __hfma2(w2, u2h2(hvA1.y), acc1);
        acc2 = __hfma2(w2, u2h2(hvA1.z), acc2);
        acc3 = __hfma2(w2, u2h2(hvA1.w), acc3);
        wu = pkA2 >> 16; w2 = u2h2(wu | (wu << 16));
        acc0 = __hfma2(w2, u2h2(hvA2.x), acc0);
        acc1 = __hfma2(w2, u2h2(hvA2.y), acc1);
        acc2 = __hfma2(w2, u2h2(hvA2.z), acc2);
        acc3 = __hfma2(w2, u2h2(hvA2.w), acc3);
        wu = pkA3 >> 16; w2 = u2h2(wu | (wu << 16));
        acc0 = __hfma2(w2, u2h2(hvA3.x), acc0);
        acc1 = __hfma2(w2, u2h2(hvA3.y), acc1);
        acc2 = __hfma2(w2, u2h2(hvA3.z), acc2);
        acc3 = __hfma2(w2, u2h2(hvA3.w), acc3);
        wu = pkB0 >> 16; w2 = u2h2(wu | (wu << 16));
        acc0 = __hfma2(w2, u2h2(hvB0.x), acc0);
        acc1 = __hfma2(w2, u2h2(hvB0.y), acc1);
        acc2 = __hfma2(w2, u2h2(hvB0.z), acc2);
        acc3 = __hfma2(w2, u2h2(hvB0.w), acc3);
        wu = pkB1 >> 16; w2 = u2h2(wu | (wu << 16));
        acc0 = __hfma2(w2, u2h2(hvB1.x), acc0);
        acc1 = __hfma2(w2, u2h2(hvB1.y), acc1);
        acc2 = __hfma2(w2, u2h2(hvB1.z), acc2);
        acc3 = __hfma2(w2, u2h2(hvB1.w), acc3);
        wu = pkB2 >> 16; w2 = u2h2(wu | (wu << 16));
        acc0 = __hfma2(w2, u2h2(hvB2.x), acc0);
        acc1 = __hfma2(w2, u2h2(hvB2.y), acc1);
        acc2 = __hfma2(w2, u2h2(hvB2.z), acc2);
        acc3 = __hfma2(w2, u2h2(hvB2.w), acc3);
        wu = pkB3 >> 16; w2 = u2h2(wu | (wu << 16));
        acc0 = __hfma2(w2, u2h2(hvB3.x), acc0);
        acc1 = __hfma2(w2, u2h2(hvB3.y), acc1);
        acc2 = __hfma2(w2, u2h2(hvB3.z), acc2);
        acc3 = __hfma2(w2, u2h2(hvB3.w), acc3);
        e += 16;
    }
    acc0 = __hadd2(acc0, u2h2(__shfl_xor(h22u(acc0), 16)));
    acc1 = __hadd2(acc1, u2h2(__shfl_xor(h22u(acc1), 16)));
    acc2 = __hadd2(acc2, u2h2(__shfl_xor(h22u(acc2), 16)));
    acc3 = __hadd2(acc3, u2h2(__shfl_xor(h22u(acc3), 16)));
    #pragma unroll
    for (int m = 1; m < 8; m <<= 1) denom += __shfl_xor(denom, m);
    float dfin = __shfl(denom, half * 32 + hd_c * 8);
    if (sub == 0) {
        float inv = 1.f / (dfin + EPS_);
        int c0 = col * 8;
        float v[8];
        v[0] = __low2float(acc0); v[1] = __high2float(acc0);
        v[2] = __low2float(acc1); v[3] = __high2float(acc1);
        v[4] = __low2float(acc2); v[5] = __high2float(acc2);
        v[6] = __low2float(acc3); v[7] = __high2float(acc3);
        unsigned int o[4];
        #pragma unroll
        for (int i = 0; i < 4; ++i) {
            float u0 = v[2 * i] * inv + b1[c0 + 2 * i];
            float u1 = v[2 * i + 1] * inv + b1[c0 + 2 * i + 1];
            u0 = 1.f / (1.f + __expf(-u0));
            u1 = 1.f / (1.f + __expf(-u1));
            o[i] = (unsigned int)f2bf(u0) | ((unsigned int)f2bf(u1) << 16);
        }
        *(uint4*)(x2 + (size_t)n * 128 + c0) = make_uint4(o[0], o[1], o[2], o[3]);
    }
}

__global__ __launch_bounds__(256, 8) void agg2_kernel(const int* __restrict__ row_ptr,
                                                      const unsigned short* __restrict__ csr16,
                                                      const unsigned int* __restrict__ h2u,
                                                      const float* __restrict__ a_src,
                                                      const float* __restrict__ a_dst,
                                                      const float* __restrict__ b2,
                                                      float* __restrict__ out) {
    int wave = (blockIdx.x * 256 + threadIdx.x) >> 6;
    int lane = threadIdx.x & 63;
    int half = lane >> 5;
    int ln = lane & 31;
    int n = wave * 2 + half;
    int j8 = ln & 7;
    int sub = (ln >> 3) & 3;       // row-slot (4 per half)
    int col = ln & 7;              // channel group: ch col*8..+7
    int rbase = half * 32 + sub;   // pack lane (+ g*4)
    float ad = a_dst[n];
    const unsigned int* h2c = h2u + col * 4;
    int e = row_ptr[n], end = row_ptr[n + 1];
    __half2 acc0 = u2h2(0u), acc1 = u2h2(0u), acc2 = u2h2(0u), acc3 = u2h2(0u);
    float denom = 0.f;
    while (e < end) {
        int rem = end - e;
        int mbA = rem > 8 ? 8 : rem;
        int remB = rem - 8;
        int mbB = remB > 8 ? 8 : (remB > 0 ? remB : 0);
        int idxA = e + (j8 < mbA ? j8 : 0);
        int idxB = (remB > 0) ? (e + 8 + (j8 < mbB ? j8 : 0)) : idxA;
        int sA = (int)csr16[idxA];
        int sB = (int)csr16[idxB];
        float lA = a_src[sA] + ad;
        float lB = a_src[sB] + ad;
        float wA = (j8 < mbA) ? lrelu_exp_s(lA) : 0.f;
        float wB = (j8 < mbB) ? lrelu_exp_s(lB) : 0.f;
        denom += wA + wB;
        unsigned int curA = ((unsigned int)f2h(wA) << 16) | (unsigned int)sA;
        unsigned int curB = ((unsigned int)f2h(wB) << 16) | (unsigned int)sB;
        unsigned int pkA0 = __shfl(curA, rbase);
        unsigned int pkA1 = __shfl(curA, rbase + 4);
        unsigned int pkB0 = __shfl(curB, rbase);
        unsigned int pkB1 = __shfl(curB, rbase + 4);
        uint4 hvA0 = *(const uint4*)(h2c + (size_t)(pkA0 & 0xffffu) * 32);
        uint4 hvA1 = *(const uint4*)(h2c + (size_t)(pkA1 & 0xffffu) * 32);
        uint4 hvB0 = *(const uint4*)(h2c + (size_t)(pkB0 & 0xffffu) * 32);
        uint4 hvB1 = *(const uint4*)(h2c + (size_t)(pkB1 & 0xffffu) * 32);
        unsigned int wu; __half2 w2;
        wu = pkA0 >> 16; w2 = u2h2(wu | (wu << 16));
        acc0 = __hfma2(w2, u2h2(hvA0.x), acc0);
        acc1 = __hfma2(w2, u2h2(hvA0.y), acc1);
        acc2 = __hfma2(w2, u2h2(hvA0.z), acc2);
        acc3 = __hfma2(w2, u2h2(hvA0.w), acc3);
        wu = pkA1 >> 16; w2 = u2h2(wu | (wu << 16));
        acc0 = __hfma2(w2, u2h2(hvA1.x), acc0);
        acc1 = __hfma2(w2, u2h2(hvA1.y), acc1);
        acc2 = __hfma2(w2, u2h2(hvA1.z), acc2);
        acc3 = __hfma2(w2, u2h2(hvA1.w), acc3);
        wu = pkB0 >> 16; w2 = u2h2(wu | (wu << 16));
        acc0 = __hfma2(w2, u2h2(hvB0.x), acc0);
        acc1 = __hfma2(w2, u2h2(hvB0.y), acc1);
        acc2 = __hfma2(w2, u2h2(hvB0.z), acc2);
        acc3 = __hfma2(w2, u2h2(hvB0.w), acc3);
        wu = pkB1 >> 16; w2 = u2h2(wu | (wu << 16));
        acc0 = __hfma2(w2, u2h2(hvB1.x), acc0);
        acc1 = __hfma2(w2, u2h2(hvB1.y), acc1);
        acc2 = __hfma2(w2, u2h2(hvB1.z), acc2);
        acc3 = __hfma2(w2, u2h2(hvB1.w), acc3);
        e += 16;
    }
    #pragma unroll
    for (int m = 8; m < 32; m <<= 1) {
        acc0 = __hadd2(acc0, u2h2(__shfl_xor(h22u(acc0), m)));
        acc1 = __hadd2(acc1, u2h2(__shfl_xor(h22u(acc1), m)));
        acc2 = __hadd2(acc2, u2h2(__shfl_xor(h22u(acc2), m)));
        acc3 = __hadd2(acc3, u2h2(__shfl_xor(h22u(acc3), m)));
    }
    #pragma unroll
    for (int m = 1; m < 8; m <<= 1) denom += __shfl_xor(denom, m);
    if (sub == 0) {
        float inv = 1.f / (denom + EPS_);
        int c0 = col * 8;
        float v[8];
        v[0] = __low2float(acc0); v[1] = __high2float(acc0);
        v[2] = __low2float(acc1); v[3] = __high2float(acc1);
        v[4] = __low2float(acc2); v[5] = __high2float(acc2);
        v[6] = __low2float(acc3); v[7] = __high2float(acc3);
        float o[8];
        #pragma unroll
        for (int i = 0; i < 8; ++i) {
            float u = v[i] * inv + b2[c0 + i];
            o[i] = 1.f / (1.f + __expf(-u));
        }
        float4* dst = (float4*)(out + (size_t)n * 64 + c0);
        dst[0] = make_float4(o[0], o[1], o[2], o[3]);
        dst[1] = make_float4(o[4], o[5], o[6], o[7]);
    }
}

// ---------------- launch ----------------

extern "C" void kernel_launch(void* const* d_in, const int* in_sizes, int n_in,
                              void* d_out, int out_size, void* d_ws, size_t ws_size,
                              hipStream_t stream) {
    (void)in_sizes; (void)n_in; (void)out_size; (void)ws_size;
    const float* x   = (const float*)d_in[0];
    const int*   ei  = (const int*)d_in[1];
    const float* W1  = (const float*)d_in[2];
    const float* as1 = (const float*)d_in[3];
    const float* ad1 = (const float*)d_in[4];
    const float* b1  = (const float*)d_in[5];
    const float* W2  = (const float*)d_in[6];
    const float* as2 = (const float*)d_in[7];
    const float* ad2 = (const float*)d_in[8];
    const float* b2  = (const float*)d_in[9];
    float* out = (float*)d_out;

    char* p = (char*)d_ws;
    auto alloc = [&](size_t bytes) -> void* {
        void* r = (void*)p;
        p += (bytes + 255) & ~(size_t)255;
        return r;
    };
    int* hist_mat   = (int*)alloc((size_t)NBUCK * PBLOCKS * 4);   // 1 MB
    int* cursor_mat = (int*)alloc((size_t)NBUCK * PBLOCKS * 4);   // 1 MB
    int* bsum       = (int*)alloc(256 * 4);
    unsigned int* edge_part = (unsigned int*)alloc((size_t)N_EDGES * 4);
    int* row_ptr    = (int*)alloc((size_t)(N_NODES + 1) * 4);
    unsigned short* csr16 = (unsigned short*)alloc((size_t)N_EDGES * 2);
    unsigned short* h1 = (unsigned short*)alloc((size_t)N_NODES * 128 * 2);  // fp16
    float* a_src1   = (float*)alloc((size_t)N_NODES * 4 * 4);
    float* a_dst1   = (float*)alloc((size_t)N_NODES * 4 * 4);
    unsigned short* x2 = (unsigned short*)alloc((size_t)N_NODES * 128 * 2);  // bf16
    unsigned short* h2 = (unsigned short*)alloc((size_t)N_NODES * 64 * 2);   // fp16
    float* a_src2   = (float*)alloc((size_t)N_NODES * 4);
    float* a_dst2   = (float*)alloc((size_t)N_NODES * 4);

    // layer-1 GEMM (+fused att1 epilogue) with coarse histogram riding along
    gemm1_hist<<<GB1 + PBLOCKS, 256, 128 * 128 * 2, stream>>>(
        x, W1, as1, ad1, ei, h1, a_src1, a_dst1, hist_mat);
    // CSR build (atomic-free radix partition)
    scan_a<<<NBUCK * PBLOCKS / 1024, 1024, 0, stream>>>(hist_mat, cursor_mat, bsum);
    scan_c<<<NBUCK * PBLOCKS / 1024, 1024, 0, stream>>>(cursor_mat, bsum);
    partition_kernel<<<PBLOCKS, 256, 0, stream>>>(ei, cursor_mat, edge_part);
    finalize_kernel<<<NBUCK, 1024, 0, stream>>>(edge_part, cursor_mat, row_ptr, csr16);
    // layer-1 aggregation
    agg1_kernel<<<N_NODES / 8, 256, 0, stream>>>(row_ptr, csr16, (const unsigned int*)h1,
                                                 a_src1, a_dst1, b1, x2);
    // layer 2
    gemm2_mfma<<<N_NODES / 64, 256, 128 * 64 * 2, stream>>>(x2, W2, as2, ad2, h2, a_src2, a_dst2);
    agg2_kernel<<<N_NODES / 8, 256, 0, stream>>>(row_ptr, csr16, (const unsigned int*)h2,
                                                 a_src2, a_dst2, b2, out);
}

// Round 3
// 220.025 us; speedup vs baseline: 1.0658x; 1.0658x over previous
//
#include <hip/hip_runtime.h>
#include <hip/hip_fp16.h>

#define N_NODES 65536
#define N_EDGES 1048576
#define NBUCK 256                 // coarse buckets (dst>>8), 256 nodes each
#define PBLOCKS 1024              // partition blocks (4 blocks/CU)
#define EPB (N_EDGES / PBLOCKS)   // 1024 edges per partition block
#define K4CAP 6144                // finalize LDS staging capacity (mean 4096, sigma 64)
#define GB1 (N_NODES / 64)        // gemm1 blocks (1024); hist blocks appended after
constexpr float NEG = 0.2f;
constexpr float EPS_ = 1e-16f;
constexpr float WSHIFT = 2.7725887f;   // ln(16): softmax-invariant shift, fp16 overflow guard

typedef __attribute__((ext_vector_type(8))) short bf16x8;
typedef __attribute__((ext_vector_type(4))) float f32x4;

__device__ __forceinline__ unsigned short f2bf(float f) {
    unsigned int u = __float_as_uint(f);
    return (unsigned short)((u + 0x7fffu + ((u >> 16) & 1u)) >> 16);
}
__device__ __forceinline__ unsigned short f2h(float f) {
    __half_raw r = __half_raw(__float2half(f));
    return r.x;
}
__device__ __forceinline__ __half2 u2h2(unsigned int u) {
    union { unsigned int u; __half2 h; } c; c.u = u; return c.h;
}
__device__ __forceinline__ unsigned int h22u(__half2 h) {
    union { unsigned int u; __half2 h; } c; c.h = h; return c.u;
}
__device__ __forceinline__ float lrelu_exp_s(float l) {
    return __expf(fmaxf(l, NEG * l) - WSHIFT);
}

// ---------------- CSR build: radix partition by dst>>8, no global atomics ----------------
// hist_mat/cursor_mat: [bucket][pblock] (bucket-major), NBUCK x PBLOCKS.
// Key invariant: PBLOCKS == 1024 == scan_a block size, so scan_a's block j IS bucket j:
// cursor_mat holds bucket-LOCAL exclusive scans and bsum[j] = global count of bucket j.
// partition/finalize fold the bucket-prefix (scan of bsum) in themselves — no scan_c.

// scan_a: block-local exclusive scan of the 256K-entry matrix (1024/block)
__global__ __launch_bounds__(1024) void scan_a(const int* __restrict__ in,
                                               int* __restrict__ out,
                                               int* __restrict__ bsum) {
    __shared__ int sm[1024];
    int t = threadIdx.x, i = blockIdx.x * 1024 + t;
    int v = in[i];
    sm[t] = v;
    __syncthreads();
    for (int off = 1; off < 1024; off <<= 1) {
        int u = (t >= off) ? sm[t - off] : 0;
        __syncthreads();
        sm[t] += u;
        __syncthreads();
    }
    out[i] = sm[t] - v;
    if (t == 1023) bsum[blockIdx.x] = sm[t];
}

__global__ __launch_bounds__(256) void partition_kernel(const int* __restrict__ ei,
                                                        const int* __restrict__ cursor_mat,
                                                        const int* __restrict__ bsum,
                                                        unsigned int* __restrict__ edge_part) {
    __shared__ int h[NBUCK];
    __shared__ int start[NBUCK];
    __shared__ int cur[NBUCK];
    __shared__ int gcur[NBUCK];
    __shared__ int bs[NBUCK];
    __shared__ unsigned int stage[EPB];
    int t = threadIdx.x;
    h[t] = 0;
    int bsv = bsum[t];
    bs[t] = bsv;
    __syncthreads();
    unsigned int ent[EPB / 256];
    int base = blockIdx.x * EPB;
    #pragma unroll
    for (int i = 0; i < EPB / 256; ++i) {
        int e = base + i * 256 + t;
        int s = ei[e], d = ei[N_EDGES + e];
        ent[i] = ((unsigned int)s << 16) | (unsigned int)d;   // src,dst both < 2^16
        atomicAdd(&h[d >> 8], 1);
    }
    __syncthreads();
    int v = h[t];
    start[t] = v;
    __syncthreads();
    // joint scan: local histogram (for start/cur) and bsum (bucket-prefix)
    for (int off = 1; off < 256; off <<= 1) {
        int u1 = (t >= off) ? start[t - off] : 0;
        int u2 = (t >= off) ? bs[t - off] : 0;
        __syncthreads();
        start[t] += u1;
        bs[t] += u2;
        __syncthreads();
    }
    int excl = start[t] - v;
    start[t] = excl;
    cur[t] = excl;
    gcur[t] = cursor_mat[t * PBLOCKS + blockIdx.x] + (bs[t] - bsv);  // + bucket base
    __syncthreads();
    #pragma unroll
    for (int i = 0; i < EPB / 256; ++i) {
        int b = (int)((ent[i] & 0xffffu) >> 8);
        int slot = atomicAdd(&cur[b], 1);
        stage[slot] = ent[i];
    }
    __syncthreads();
    int s0 = t * (EPB / 256);
    #pragma unroll
    for (int i = 0; i < EPB / 256; ++i) {
        unsigned int p = stage[s0 + i];
        int b = (int)((p & 0xffffu) >> 8);
        edge_part[gcur[b] + (s0 + i - start[b])] = p;
    }
}

// finalize: 1024 threads/block (16 waves/CU), csr_src as ushort
__global__ __launch_bounds__(1024) void finalize_kernel(const unsigned int* __restrict__ edge_part,
                                                        const int* __restrict__ cursor_mat,
                                                        const int* __restrict__ bsum,
                                                        int* __restrict__ row_ptr,
                                                        unsigned short* __restrict__ csr16) {
    __shared__ int h[256];
    __shared__ int sc[256];
    __shared__ int cur[256];
    __shared__ int bs[256];
    __shared__ unsigned short stage[K4CAP];
    int t = threadIdx.x;
    int b = blockIdx.x;
    if (b == NBUCK - 1 && t == 0) row_ptr[N_NODES] = N_EDGES;
    // bucket-prefix from bsum (inclusive scan in LDS)
    if (t < 256) bs[t] = bsum[t];
    __syncthreads();
    for (int off = 1; off < 256; off <<= 1) {
        int u = (t < 256 && t >= off) ? bs[t - off] : 0;
        __syncthreads();
        if (t < 256) bs[t] += u;
        __syncthreads();
    }
    int cs = cursor_mat[b * PBLOCKS] + (b ? bs[b - 1] : 0);
    int ce = (b == NBUCK - 1) ? N_EDGES : cursor_mat[(b + 1) * PBLOCKS] + bs[b];
    int cnt = ce - cs;
    if (t < 256) h[t] = 0;
    __syncthreads();
    for (int i = t; i < cnt; i += 1024)
        atomicAdd(&h[edge_part[cs + i] & 0xffu], 1);
    __syncthreads();
    int v = 0;
    if (t < 256) { v = h[t]; sc[t] = v; }
    __syncthreads();
    for (int off = 1; off < 256; off <<= 1) {
        int u = (t < 256 && t >= off) ? sc[t - off] : 0;
        __syncthreads();
        if (t < 256) sc[t] += u;
        __syncthreads();
    }
    if (t < 256) {
        int excl = sc[t] - v;
        row_ptr[b * 256 + t] = cs + excl;
        cur[t] = excl;
    }
    __syncthreads();
    if (cnt <= K4CAP) {
        for (int i = t; i < cnt; i += 1024) {
            unsigned int p = edge_part[cs + i];
            int slot = atomicAdd(&cur[p & 0xffu], 1);
            stage[slot] = (unsigned short)(p >> 16);
        }
        __syncthreads();
        for (int i = t; i < cnt; i += 1024)
            csr16[cs + i] = stage[i];
    } else {
        for (int i = t; i < cnt; i += 1024) {
            unsigned int p = edge_part[cs + i];
            int slot = atomicAdd(&cur[p & 0xffu], 1);
            csr16[cs + slot] = (unsigned short)(p >> 16);
        }
    }
}

// ---------------- GEMM via MFMA 16x16x32 bf16 (fp32 accum, fp16 out) ----------------
// layer 1: fp32 X input; att1 fused into epilogue (a_src/a_dst from fp32 accumulators);
// coarse_hist fused as trailing block range (BW-light, hides under MFMA blocks).

__global__ __launch_bounds__(256) void gemm1_hist(const float* __restrict__ X,
                                                  const float* __restrict__ W,
                                                  const float* __restrict__ as_w,
                                                  const float* __restrict__ ad_w,
                                                  const int* __restrict__ ei,
                                                  unsigned short* __restrict__ H,
                                                  float* __restrict__ a_src,
                                                  float* __restrict__ a_dst,
                                                  int* __restrict__ hist_mat) {
    extern __shared__ unsigned short Wl[];
    int t = threadIdx.x;
    if (blockIdx.x >= GB1) {
        // ---- coarse histogram path (block-uniform branch) ----
        int* hs = (int*)Wl;
        int pb = blockIdx.x - GB1;
        hs[t] = 0;
        __syncthreads();
        int base = pb * EPB;
        #pragma unroll
        for (int i = 0; i < EPB / 256; ++i) {
            int d = ei[N_EDGES + base + i * 256 + t];
            atomicAdd(&hs[d >> 8], 1);
        }
        __syncthreads();
        hist_mat[t * PBLOCKS + pb] = hs[t];
        return;
    }
    constexpr int OUTC = 128;
    constexpr int NT = OUTC / 16;
    for (int idx = t; idx < OUTC * 128; idx += 256) {
        int j = idx & 7;
        int ln = (idx >> 3) & 63;
        int fc = idx >> 9;
        int kc = fc & 3, ct = fc >> 2;
        int k = kc * 32 + (ln >> 4) * 8 + j;
        int nn = ct * 16 + (ln & 15);
        Wl[idx] = (unsigned short)f2bf(W[k * OUTC + nn]);
    }
    __syncthreads();
    int wave = t >> 6, lane = t & 63;
    int m = lane & 15, quad = lane >> 4;
    int node_base = blockIdx.x * 64 + wave * 16;
    const float* xrow = X + (size_t)(node_base + m) * 128 + quad * 8;
    bf16x8 a[4];
    #pragma unroll
    for (int kc = 0; kc < 4; ++kc) {
        float4 u = *(const float4*)(xrow + kc * 32);
        float4 v = *(const float4*)(xrow + kc * 32 + 4);
        bf16x8 af;
        af[0] = (short)f2bf(u.x); af[1] = (short)f2bf(u.y);
        af[2] = (short)f2bf(u.z); af[3] = (short)f2bf(u.w);
        af[4] = (short)f2bf(v.x); af[5] = (short)f2bf(v.y);
        af[6] = (short)f2bf(v.z); af[7] = (short)f2bf(v.w);
        a[kc] = af;
    }
    float asv[NT], adv[NT];
    #pragma unroll
    for (int ct = 0; ct < NT; ++ct) {
        asv[ct] = as_w[ct * 16 + m];
        adv[ct] = ad_w[ct * 16 + m];
    }
    float ps[4][4] = {};
    float pd[4][4] = {};
    #pragma unroll
    for (int ct = 0; ct < NT; ++ct) {
        f32x4 acc = {0.f, 0.f, 0.f, 0.f};
        #pragma unroll
        for (int kc = 0; kc < 4; ++kc) {
            bf16x8 bfr = *(const bf16x8*)(Wl + ((ct * 4 + kc) * 64 + lane) * 8);
            acc = __builtin_amdgcn_mfma_f32_16x16x32_bf16(a[kc], bfr, acc, 0, 0, 0);
        }
        int hh = ct >> 1;   // head = channel>>5 = ct>>1 (m<16)
        #pragma unroll
        for (int r = 0; r < 4; ++r) {
            H[(size_t)(node_base + quad * 4 + r) * OUTC + ct * 16 + m] = f2h(acc[r]);
            ps[r][hh] += acc[r] * asv[ct];
            pd[r][hh] += acc[r] * adv[ct];
        }
    }
    // reduce partial dots across the 16 m-lanes (quad-preserving masks)
    #pragma unroll
    for (int r = 0; r < 4; ++r) {
        #pragma unroll
        for (int hh = 0; hh < 4; ++hh) {
            float s = ps[r][hh], d = pd[r][hh];
            #pragma unroll
            for (int msk = 1; msk < 16; msk <<= 1) {
                s += __shfl_xor(s, msk);
                d += __shfl_xor(d, msk);
            }
            if (m == 0) {
                int node = node_base + quad * 4 + r;
                a_src[node * 4 + hh] = s;
                a_dst[node * 4 + hh] = d;
            }
        }
    }
}

// layer 2: bf16 X input; att2 fused into epilogue

__global__ __launch_bounds__(256) void gemm2_mfma(const unsigned short* __restrict__ X,
                                                  const float* __restrict__ W,
                                                  const float* __restrict__ as_w,
                                                  const float* __restrict__ ad_w,
                                                  unsigned short* __restrict__ H,
                                                  float* __restrict__ a_src,
                                                  float* __restrict__ a_dst) {
    constexpr int OUTC = 64;
    constexpr int NT = OUTC / 16;
    extern __shared__ unsigned short Wl[];
    int t = threadIdx.x;
    for (int idx = t; idx < OUTC * 128; idx += 256) {
        int j = idx & 7;
        int ln = (idx >> 3) & 63;
        int fc = idx >> 9;
        int kc = fc & 3, ct = fc >> 2;
        int k = kc * 32 + (ln >> 4) * 8 + j;
        int nn = ct * 16 + (ln & 15);
        Wl[idx] = (unsigned short)f2bf(W[k * OUTC + nn]);
    }
    __syncthreads();
    int wave = t >> 6, lane = t & 63;
    int m = lane & 15, quad = lane >> 4;
    int node_base = blockIdx.x * 64 + wave * 16;
    const unsigned short* xrow = X + (size_t)(node_base + m) * 128 + quad * 8;
    bf16x8 a[4];
    #pragma unroll
    for (int kc = 0; kc < 4; ++kc) a[kc] = *(const bf16x8*)(xrow + kc * 32);
    float asv[NT], adv[NT];
    #pragma unroll
    for (int ct = 0; ct < NT; ++ct) {
        asv[ct] = as_w[ct * 16 + m];
        adv[ct] = ad_w[ct * 16 + m];
    }
    float ps[4] = {};
    float pd[4] = {};
    #pragma unroll
    for (int ct = 0; ct < NT; ++ct) {
        f32x4 acc = {0.f, 0.f, 0.f, 0.f};
        #pragma unroll
        for (int kc = 0; kc < 4; ++kc) {
            bf16x8 bfr = *(const bf16x8*)(Wl + ((ct * 4 + kc) * 64 + lane) * 8);
            acc = __builtin_amdgcn_mfma_f32_16x16x32_bf16(a[kc], bfr, acc, 0, 0, 0);
        }
        #pragma unroll
        for (int r = 0; r < 4; ++r) {
            H[(size_t)(node_base + quad * 4 + r) * OUTC + ct * 16 + m] = f2h(acc[r]);
            ps[r] += acc[r] * asv[ct];
            pd[r] += acc[r] * adv[ct];
        }
    }
    #pragma unroll
    for (int r = 0; r < 4; ++r) {
        float s = ps[r], d = pd[r];
        #pragma unroll
        for (int msk = 1; msk < 16; msk <<= 1) {
            s += __shfl_xor(s, msk);
            d += __shfl_xor(d, msk);
        }
        if (m == 0) {
            int node = node_base + quad * 4 + r;
            a_src[node] = s;
            a_dst[node] = d;
        }
    }
}

// ---------------- edge aggregation: TWO nodes per wave, 16 edges/node/iter ----------
// Two 8-edge sub-batches per iteration; all 8 (agg1) / 4 (agg2) row-gathers issued
// before any hfma. NO min-wave launch bound: the in-flight window needs ~60 live
// VGPRs — capping at 64 (256,8) spilled to scratch (R2: WRITE_SIZE 16->57 MB).

__global__ __launch_bounds__(256) void agg1_kernel(const int* __restrict__ row_ptr,
                                                   const unsigned short* __restrict__ csr16,
                                                   const unsigned int* __restrict__ h1u,
                                                   const float* __restrict__ a_src,
                                                   const float* __restrict__ a_dst,
                                                   const float* __restrict__ b1,
                                                   unsigned short* __restrict__ x2) {
    int wave = (blockIdx.x * 256 + threadIdx.x) >> 6;
    int lane = threadIdx.x & 63;
    int half = lane >> 5;
    int ln = lane & 31;
    int n = wave * 2 + half;
    int j8 = ln & 7;               // batch edge slot
    int whead = ln >> 3;           // head for w-compute
    int sub = ln >> 4;             // row-slot within half (0/1)
    int col = ln & 15;             // channel group: ch col*8..+7
    int hd_c = col >> 2;           // head of this lane's channels
    int rbase = half * 32 + hd_c * 8 + sub;   // pack-lane base (+ g*2)
    float adw = a_dst[n * 4 + whead];
    const unsigned int* h1c = h1u + col * 4;
    const float* asw = a_src + whead;
    int e = row_ptr[n], end = row_ptr[n + 1];
    __half2 acc0 = u2h2(0u), acc1 = u2h2(0u), acc2 = u2h2(0u), acc3 = u2h2(0u);
    float denom = 0.f;
    while (e < end) {
        int rem = end - e;
        int mbA = rem > 8 ? 8 : rem;
        int remB = rem - 8;
        int mbB = remB > 8 ? 8 : (remB > 0 ? remB : 0);
        int idxA = e + (j8 < mbA ? j8 : 0);
        int idxB = (remB > 0) ? (e + 8 + (j8 < mbB ? j8 : 0)) : idxA;
        int sA = (int)csr16[idxA];
        int sB = (int)csr16[idxB];
        float lA = asw[sA * 4] + adw;
        float lB = asw[sB * 4] + adw;
        float wA = (j8 < mbA) ? lrelu_exp_s(lA) : 0.f;
        float wB = (j8 < mbB) ? lrelu_exp_s(lB) : 0.f;
        denom += wA + wB;
        unsigned int curA = ((unsigned int)f2h(wA) << 16) | (unsigned int)sA;
        unsigned int curB = ((unsigned int)f2h(wB) << 16) | (unsigned int)sB;
        unsigned int pkA0 = __shfl(curA, rbase);
        unsigned int pkA1 = __shfl(curA, rbase + 2);
        unsigned int pkA2 = __shfl(curA, rbase + 4);
        unsigned int pkA3 = __shfl(curA, rbase + 6);
        unsigned int pkB0 = __shfl(curB, rbase);
        unsigned int pkB1 = __shfl(curB, rbase + 2);
        unsigned int pkB2 = __shfl(curB, rbase + 4);
        unsigned int pkB3 = __shfl(curB, rbase + 6);
        uint4 hvA0 = *(const uint4*)(h1c + (size_t)(pkA0 & 0xffffu) * 64);
        uint4 hvA1 = *(const uint4*)(h1c + (size_t)(pkA1 & 0xffffu) * 64);
        uint4 hvA2 = *(const uint4*)(h1c + (size_t)(pkA2 & 0xffffu) * 64);
        uint4 hvA3 = *(const uint4*)(h1c + (size_t)(pkA3 & 0xffffu) * 64);
        uint4 hvB0 = *(const uint4*)(h1c + (size_t)(pkB0 & 0xffffu) * 64);
        uint4 hvB1 = *(const uint4*)(h1c + (size_t)(pkB1 & 0xffffu) * 64);
        uint4 hvB2 = *(const uint4*)(h1c + (size_t)(pkB2 & 0xffffu) * 64);
        uint4 hvB3 = *(const uint4*)(h1c + (size_t)(pkB3 & 0xffffu) * 64);
        unsigned int wu; __half2 w2;
        wu = pkA0 >> 16; w2 = u2h2(wu | (wu << 16));
        acc0 = __hfma2(w2, u2h2(hvA0.x), acc0);
        acc1 = __hfma2(w2, u2h2(hvA0.y), acc1);
        acc2 = __hfma2(w2, u2h2(hvA0.z), acc2);
        acc3 = __hfma2(w2, u2h2(hvA0.w), acc3);
        wu = pkA1 >> 16; w2 = u2h2(wu | (wu << 16));
        acc0 = __hfma2(w2, u2h2(hvA1.x), acc0);
        acc1 = __hfma2(w2, u2h2(hvA1.y), acc1);
        acc2 = __hfma2(w2, u2h2(hvA1.z), acc2);
        acc3 = __hfma2(w2, u2h2(hvA1.w), acc3);
        wu = pkA2 >> 16; w2 = u2h2(wu | (wu << 16));
        acc0 = __hfma2(w2, u2h2(hvA2.x), acc0);
        acc1 = __hfma2(w2, u2h2(hvA2.y), acc1);
        acc2 = __hfma2(w2, u2h2(hvA2.z), acc2);
        acc3 = __hfma2(w2, u2h2(hvA2.w), acc3);
        wu = pkA3 >> 16; w2 = u2h2(wu | (wu << 16));
        acc0 = __hfma2(w2, u2h2(hvA3.x), acc0);
        acc1 = __hfma2(w2, u2h2(hvA3.y), acc1);
        acc2 = __hfma2(w2, u2h2(hvA3.z), acc2);
        acc3 = __hfma2(w2, u2h2(hvA3.w), acc3);
        wu = pkB0 >> 16; w2 = u2h2(wu | (wu << 16));
        acc0 = __hfma2(w2, u2h2(hvB0.x), acc0);
        acc1 = __hfma2(w2, u2h2(hvB0.y), acc1);
        acc2 = __hfma2(w2, u2h2(hvB0.z), acc2);
        acc3 = __hfma2(w2, u2h2(hvB0.w), acc3);
        wu = pkB1 >> 16; w2 = u2h2(wu | (wu << 16));
        acc0 = __hfma2(w2, u2h2(hvB1.x), acc0);
        acc1 = __hfma2(w2, u2h2(hvB1.y), acc1);
        acc2 = __hfma2(w2, u2h2(hvB1.z), acc2);
        acc3 = __hfma2(w2, u2h2(hvB1.w), acc3);
        wu = pkB2 >> 16; w2 = u2h2(wu | (wu << 16));
        acc0 = __hfma2(w2, u2h2(hvB2.x), acc0);
        acc1 = __hfma2(w2, u2h2(hvB2.y), acc1);
        acc2 = __hfma2(w2, u2h2(hvB2.z), acc2);
        acc3 = __hfma2(w2, u2h2(hvB2.w), acc3);
        wu = pkB3 >> 16; w2 = u2h2(wu | (wu << 16));
        acc0 = __hfma2(w2, u2h2(hvB3.x), acc0);
        acc1 = __hfma2(w2, u2h2(hvB3.y), acc1);
        acc2 = __hfma2(w2, u2h2(hvB3.z), acc2);
        acc3 = __hfma2(w2, u2h2(hvB3.w), acc3);
        e += 16;
    }
    acc0 = __hadd2(acc0, u2h2(__shfl_xor(h22u(acc0), 16)));
    acc1 = __hadd2(acc1, u2h2(__shfl_xor(h22u(acc1), 16)));
    acc2 = __hadd2(acc2, u2h2(__shfl_xor(h22u(acc2), 16)));
    acc3 = __hadd2(acc3, u2h2(__shfl_xor(h22u(acc3), 16)));
    #pragma unroll
    for (int m = 1; m < 8; m <<= 1) denom += __shfl_xor(denom, m);
    float dfin = __shfl(denom, half * 32 + hd_c * 8);
    if (sub == 0) {
        float inv = 1.f / (dfin + EPS_);
        int c0 = col * 8;
        float v[8];
        v[0] = __low2float(acc0); v[1] = __high2float(acc0);
        v[2] = __low2float(acc1); v[3] = __high2float(acc1);
        v[4] = __low2float(acc2); v[5] = __high2float(acc2);
        v[6] = __low2float(acc3); v[7] = __high2float(acc3);
        unsigned int o[4];
        #pragma unroll
        for (int i = 0; i < 4; ++i) {
            float u0 = v[2 * i] * inv + b1[c0 + 2 * i];
            float u1 = v[2 * i + 1] * inv + b1[c0 + 2 * i + 1];
            u0 = 1.f / (1.f + __expf(-u0));
            u1 = 1.f / (1.f + __expf(-u1));
            o[i] = (unsigned int)f2bf(u0) | ((unsigned int)f2bf(u1) << 16);
        }
        *(uint4*)(x2 + (size_t)n * 128 + c0) = make_uint4(o[0], o[1], o[2], o[3]);
    }
}

__global__ __launch_bounds__(256) void agg2_kernel(const int* __restrict__ row_ptr,
                                                   const unsigned short* __restrict__ csr16,
                                                   const unsigned int* __restrict__ h2u,
                                                   const float* __restrict__ a_src,
                                                   const float* __restrict__ a_dst,
                                                   const float* __restrict__ b2,
                                                   float* __restrict__ out) {
    int wave = (blockIdx.x * 256 + threadIdx.x) >> 6;
    int lane = threadIdx.x & 63;
    int half = lane >> 5;
    int ln = lane & 31;
    int n = wave * 2 + half;
    int j8 = ln & 7;
    int sub = (ln >> 3) & 3;       // row-slot (4 per half)
    int col = ln & 7;              // channel group: ch col*8..+7
    int rbase = half * 32 + sub;   // pack lane (+ g*4)
    float ad = a_dst[n];
    const unsigned int* h2c = h2u + col * 4;
    int e = row_ptr[n], end = row_ptr[n + 1];
    __half2 acc0 = u2h2(0u), acc1 = u2h2(0u), acc2 = u2h2(0u), acc3 = u2h2(0u);
    float denom = 0.f;
    while (e < end) {
        int rem = end - e;
        int mbA = rem > 8 ? 8 : rem;
        int remB = rem - 8;
        int mbB = remB > 8 ? 8 : (remB > 0 ? remB : 0);
        int idxA = e + (j8 < mbA ? j8 : 0);
        int idxB = (remB > 0) ? (e + 8 + (j8 < mbB ? j8 : 0)) : idxA;
        int sA = (int)csr16[idxA];
        int sB = (int)csr16[idxB];
        float lA = a_src[sA] + ad;
        float lB = a_src[sB] + ad;
        float wA = (j8 < mbA) ? lrelu_exp_s(lA) : 0.f;
        float wB = (j8 < mbB) ? lrelu_exp_s(lB) : 0.f;
        denom += wA + wB;
        unsigned int curA = ((unsigned int)f2h(wA) << 16) | (unsigned int)sA;
        unsigned int curB = ((unsigned int)f2h(wB) << 16) | (unsigned int)sB;
        unsigned int pkA0 = __shfl(curA, rbase);
        unsigned int pkA1 = __shfl(curA, rbase + 4);
        unsigned int pkB0 = __shfl(curB, rbase);
        unsigned int pkB1 = __shfl(curB, rbase + 4);
        uint4 hvA0 = *(const uint4*)(h2c + (size_t)(pkA0 & 0xffffu) * 32);
        uint4 hvA1 = *(const uint4*)(h2c + (size_t)(pkA1 & 0xffffu) * 32);
        uint4 hvB0 = *(const uint4*)(h2c + (size_t)(pkB0 & 0xffffu) * 32);
        uint4 hvB1 = *(const uint4*)(h2c + (size_t)(pkB1 & 0xffffu) * 32);
        unsigned int wu; __half2 w2;
        wu = pkA0 >> 16; w2 = u2h2(wu | (wu << 16));
        acc0 = __hfma2(w2, u2h2(hvA0.x), acc0);
        acc1 = __hfma2(w2, u2h2(hvA0.y), acc1);
        acc2 = __hfma2(w2, u2h2(hvA0.z), acc2);
        acc3 = __hfma2(w2, u2h2(hvA0.w), acc3);
        wu = pkA1 >> 16; w2 = u2h2(wu | (wu << 16));
        acc0 = __hfma2(w2, u2h2(hvA1.x), acc0);
        acc1 = __hfma2(w2, u2h2(hvA1.y), acc1);
        acc2 = __hfma2(w2, u2h2(hvA1.z), acc2);
        acc3 = __hfma2(w2, u2h2(hvA1.w), acc3);
        wu = pkB0 >> 16; w2 = u2h2(wu | (wu << 16));
        acc0 = __hfma2(w2, u2h2(hvB0.x), acc0);
        acc1 = __hfma2(w2, u2h2(hvB0.y), acc1);
        acc2 = __hfma2(w2, u2h2(hvB0.z), acc2);
        acc3 = __hfma2(w2, u2h2(hvB0.w), acc3);
        wu = pkB1 >> 16; w2 = u2h2(wu | (wu << 16));
        acc0 = __hfma2(w2, u2h2(hvB1.x), acc0);
        acc1 = __hfma2(w2, u2h2(hvB1.y), acc1);
        acc2 = __hfma2(w2, u2h2(hvB1.z), acc2);
        acc3 = __hfma2(w2, u2h2(hvB1.w), acc3);
        e += 16;
    }
    #pragma unroll
    for (int m = 8; m < 32; m <<= 1) {
        acc0 = __hadd2(acc0, u2h2(__shfl_xor(h22u(acc0), m)));
        acc1 = __hadd2(acc1, u2h2(__shfl_xor(h22u(acc1), m)));
        acc2 = __hadd2(acc2, u2h2(__shfl_xor(h22u(acc2), m)));
        acc3 = __hadd2(acc3, u2h2(__shfl_xor(h22u(acc3), m)));
    }
    #pragma unroll
    for (int m = 1; m < 8; m <<= 1) denom += __shfl_xor(denom, m);
    if (sub == 0) {
        float inv = 1.f / (denom + EPS_);
        int c0 = col * 8;
        float v[8];
        v[0] = __low2float(acc0); v[1] = __high2float(acc0);
        v[2] = __low2float(acc1); v[3] = __high2float(acc1);
        v[4] = __low2float(acc2); v[5] = __high2float(acc2);
        v[6] = __low2float(acc3); v[7] = __high2float(acc3);
        float o[8];
        #pragma unroll
        for (int i = 0; i < 8; ++i) {
            float u = v[i] * inv + b2[c0 + i];
            o[i] = 1.f / (1.f + __expf(-u));
        }
        float4* dst = (float4*)(out + (size_t)n * 64 + c0);
        dst[0] = make_float4(o[0], o[1], o[2], o[3]);
        dst[1] = make_float4(o[4], o[5], o[6], o[7]);
    }
}

// ---------------- launch ----------------

extern "C" void kernel_launch(void* const* d_in, const int* in_sizes, int n_in,
                              void* d_out, int out_size, void* d_ws, size_t ws_size,
                              hipStream_t stream) {
    (void)in_sizes; (void)n_in; (void)out_size; (void)ws_size;
    const float* x   = (const float*)d_in[0];
    const int*   ei  = (const int*)d_in[1];
    const float* W1  = (const float*)d_in[2];
    const float* as1 = (const float*)d_in[3];
    const float* ad1 = (const float*)d_in[4];
    const float* b1  = (const float*)d_in[5];
    const float* W2  = (const float*)d_in[6];
    const float* as2 = (const float*)d_in[7];
    const float* ad2 = (const float*)d_in[8];
    const float* b2  = (const float*)d_in[9];
    float* out = (float*)d_out;

    char* p = (char*)d_ws;
    auto alloc = [&](size_t bytes) -> void* {
        void* r = (void*)p;
        p += (bytes + 255) & ~(size_t)255;
        return r;
    };
    int* hist_mat   = (int*)alloc((size_t)NBUCK * PBLOCKS * 4);   // 1 MB
    int* cursor_mat = (int*)alloc((size_t)NBUCK * PBLOCKS * 4);   // 1 MB
    int* bsum       = (int*)alloc(256 * 4);
    unsigned int* edge_part = (unsigned int*)alloc((size_t)N_EDGES * 4);
    int* row_ptr    = (int*)alloc((size_t)(N_NODES + 1) * 4);
    unsigned short* csr16 = (unsigned short*)alloc((size_t)N_EDGES * 2);
    unsigned short* h1 = (unsigned short*)alloc((size_t)N_NODES * 128 * 2);  // fp16
    float* a_src1   = (float*)alloc((size_t)N_NODES * 4 * 4);
    float* a_dst1   = (float*)alloc((size_t)N_NODES * 4 * 4);
    unsigned short* x2 = (unsigned short*)alloc((size_t)N_NODES * 128 * 2);  // bf16
    unsigned short* h2 = (unsigned short*)alloc((size_t)N_NODES * 64 * 2);   // fp16
    float* a_src2   = (float*)alloc((size_t)N_NODES * 4);
    float* a_dst2   = (float*)alloc((size_t)N_NODES * 4);

    // layer-1 GEMM (+fused att1 epilogue) with coarse histogram riding along
    gemm1_hist<<<GB1 + PBLOCKS, 256, 128 * 128 * 2, stream>>>(
        x, W1, as1, ad1, ei, h1, a_src1, a_dst1, hist_mat);
    // CSR build (atomic-free radix partition; bucket-prefix folded into consumers)
    scan_a<<<NBUCK * PBLOCKS / 1024, 1024, 0, stream>>>(hist_mat, cursor_mat, bsum);
    partition_kernel<<<PBLOCKS, 256, 0, stream>>>(ei, cursor_mat, bsum, edge_part);
    finalize_kernel<<<NBUCK, 1024, 0, stream>>>(edge_part, cursor_mat, bsum, row_ptr, csr16);
    // layer-1 aggregation
    agg1_kernel<<<N_NODES / 8, 256, 0, stream>>>(row_ptr, csr16, (const unsigned int*)h1,
                                                 a_src1, a_dst1, b1, x2);
    // layer 2
    gemm2_mfma<<<N_NODES / 64, 256, 128 * 64 * 2, stream>>>(x2, W2, as2, ad2, h2, a_src2, a_dst2);
    agg2_kernel<<<N_NODES / 8, 256, 0, stream>>>(row_ptr, csr16, (const unsigned int*)h2,
                                                 a_src2, a_dst2, b2, out);
}